// Round 9
// baseline (234.929 us; speedup 1.0000x reference)
//
#include <hip/hip_runtime.h>

typedef short  s16x8 __attribute__((ext_vector_type(8)));   // 8 bf16 bit patterns
typedef float  f32x4 __attribute__((ext_vector_type(4)));
typedef float  f32x2 __attribute__((ext_vector_type(2)));
typedef unsigned int u32;
typedef unsigned int u32x4 __attribute__((ext_vector_type(4)));
typedef unsigned short u16;

#define DEVI static __device__ __forceinline__

#if __has_builtin(__builtin_amdgcn_exp2f)
#define EXP2(v) __builtin_amdgcn_exp2f(v)   // raw v_exp_f32 (R11-proven)
#else
#define EXP2(v) exp2f(v)
#endif

constexpr int T_   = 128;
constexpr int F_   = 14;
constexpr int H_   = 64;
constexpr int BPB  = 16;   // batch rows computed per block (MFMA M dim)
constexpr int BSTR = 8;    // block-start stride: adjacent blocks overlap by 8
                           // rows (redundant identical compute) -> 512 blocks
                           // -> 2 blocks/CU co-resident -> 2 waves/SIMD TLP
constexpr int BTOT = 4096; // total batch rows
constexpr int K_   = 8;    // timesteps per epoch (chunk)
constexpr int NCH  = T_ / K_;   // 16 chunks

// x-frag is identically ZERO for lanes g>=2 (only 14 features) -> xbuf needs
// only 32 lanes.  LDS total 72 KiB -> TWO blocks fit in 160 KiB with headroom.
constexpr int HF_BYTES   = 2 * 2 * K_ * 2 * 64 * 16;   // 65536
constexpr int XBUF_BYTES = 2 * K_ * 32 * 16;           // 8192 (32 lanes only)
constexpr int SMEM_BYTES = HF_BYTES + XBUF_BYTES;      // 73728 (x2 = 144 KiB/CU)

DEVI u16 f2bf(float f) {                     // RNE, one-time weight convert
  u32 u = __builtin_bit_cast(u32, f);
  u += 0x7fffu + ((u >> 16) & 1u);
  return (u16)(u >> 16);
}
// HW packed bf16 convert (RNE): 1 instr replaces 5-op manual pack.
DEVI u32 cvtpk(float a, float b) {           // lo16 = bf16(a), hi16 = bf16(b)
  u32 r;
  asm("v_cvt_pk_bf16_f32 %0, %1, %2" : "=v"(r) : "v"(a), "v"(b));
  return r;
}
// B-frag kt from tanh'd acc tiles: elements 0-3 = tile kt, 4-7 = tile kt+2
DEVI s16x8 packfrag(const f32x4& a, const f32x4& b) {
  u32x4 p;
  p[0] = cvtpk(a[0], a[1]); p[1] = cvtpk(a[2], a[3]);
  p[2] = cvtpk(b[0], b[1]); p[3] = cvtpk(b[2], b[3]);
  return __builtin_bit_cast(s16x8, p);
}
// tanh; mul/add/fma as packed fp32 (bit-identical to scalar), trans scalar.
DEVI f32x4 tanh4(const f32x4& v) {
  const f32x4 kC = -2.8853900817779268f;
  f32x4 t = v * kC;                          // 2x v_pk_mul_f32
  f32x4 e;
  e[0] = EXP2(t[0]); e[1] = EXP2(t[1]);
  e[2] = EXP2(t[2]); e[3] = EXP2(t[3]);
  const f32x4 kOne = 1.0f;
  f32x4 d = e + kOne;                        // 2x v_pk_add_f32
  f32x4 r;
  r[0] = __builtin_amdgcn_rcpf(d[0]); r[1] = __builtin_amdgcn_rcpf(d[1]);
  r[2] = __builtin_amdgcn_rcpf(d[2]); r[3] = __builtin_amdgcn_rcpf(d[3]);
  const f32x4 kTwo = 2.0f, kNegOne = -1.0f;
  return __builtin_elementwise_fma(kTwo, r, kNegOne);   // 2x v_pk_fma_f32
}
DEVI f32x4 MFMA(s16x8 a, s16x8 b, f32x4 c) {
  return __builtin_amdgcn_mfma_f32_16x16x32_bf16(a, b, c, 0, 0, 0);
}
DEVI s16x8 ldrow8(const float* p) {          // 8 contiguous fp32 -> bf16 A-frag
  const f32x4 a = ((const f32x4*)p)[0];
  const f32x4 b = ((const f32x4*)p)[1];
  s16x8 r;
  r[0] = (short)f2bf(a[0]); r[1] = (short)f2bf(a[1]);
  r[2] = (short)f2bf(a[2]); r[3] = (short)f2bf(a[3]);
  r[4] = (short)f2bf(b[0]); r[5] = (short)f2bf(b[1]);
  r[6] = (short)f2bf(b[2]); r[7] = (short)f2bf(b[3]);
  return r;
}

// R9 = R5's PROVEN-CORRECT kernel (absmax exactly 5.859375e-3) minus R5's two
// defects.  R5 validated duplicate-work TLP (2 blocks/CU, 2 waves/SIMD) but
// (a) __launch_bounds__(256,2) clamped VGPR to 128 -> 14 MB of scratch spill
// traffic per dispatch, and (b) LDS 80 KiB x2 = exact-fit risk.  This round:
// (a) launch_bounds (256,1) -> compiler uses ~160 VGPR like R3, no spill
//     (2 waves/SIMD only needs <=256 VGPR; the HW scheduler, not
//     launch_bounds, decides co-residency);
// (b) xbuf stored for 32 lanes only (x-frags for g>=2 are identically zero
//     since F=14 < 16) -> LDS 72 KiB -> 2 blocks = 144 KiB < 160 KiB.
// The 8-wave layer-split design (R6-R8) is abandoned: twice failed numerically
// with plumbing that survived 3 inspections — not worth a third blind debug.
// Everything else is R5/R3-verbatim: waves 0-2 own layer w (R8 math/layout),
// chunk pipeline K_=8, producer wave 3, bc-seeded q, cvt_pk, packed-fp32 tanh.
__global__ __launch_bounds__(256, 1) void rnn_ck(
    const float* __restrict__ x,
    const float* __restrict__ Wih0, const float* __restrict__ Whh0,
    const float* __restrict__ bih0, const float* __restrict__ bhh0,
    const float* __restrict__ Wih1, const float* __restrict__ Whh1,
    const float* __restrict__ bih1, const float* __restrict__ bhh1,
    const float* __restrict__ Wih2, const float* __restrict__ Whh2,
    const float* __restrict__ bih2, const float* __restrict__ bhh2,
    const float* __restrict__ fc1w, const float* __restrict__ fc1b,
    const float* __restrict__ fc2w, const float* __restrict__ fc2b,
    float* __restrict__ out)
{
  extern __shared__ __align__(16) char smem[];
  // hf[par][layer01][k][frag][lane], xbuf[par][k][lane<32]
  u32x4 (*hf)[2][K_][2][64] = (u32x4 (*)[2][K_][2][64])smem;
  u32x4 (*xbuf)[K_][32]     = (u32x4 (*)[K_][32])(smem + HF_BYTES);

  const int tid  = threadIdx.x;
  const int w    = tid >> 6;        // waves 0-2: layer id; wave 3: x producer
  const int lane = tid & 63;
  const int g    = lane >> 4;
  const int m    = lane & 15;
  const int b0   = blockIdx.x * BSTR;
  // clamped global row: last block's rows 8..15 fold to 4095 (identical
  // values recomputed; duplicate writes of identical data are benign)
  const int row  = (b0 + m < BTOT) ? (b0 + m) : (BTOT - 1);

  f32x4 z4; z4[0] = 0.f; z4[1] = 0.f; z4[2] = 0.f; z4[3] = 0.f;
  s16x8 zf;
  #pragma unroll
  for (int i = 0; i < 8; i++) zf[i] = 0;

  // ---- per-wave (per-layer) weights, register-resident (waves 0-2 only) ----
  s16x8 Ax[4], Ai[4][2], Ah[4][2];
  f32x4 bc[4];
  if (w < 3) {
    const float* Wi = Wih1; const float* Wh = Whh0;
    const float* bi = bih0; const float* bh = bhh0;
    if (w == 1)      { Wi = Wih1; Wh = Whh1; bi = bih1; bh = bhh1; }
    else if (w == 2) { Wi = Wih2; Wh = Whh2; bi = bih2; bh = bhh2; }
    #pragma unroll
    for (int n = 0; n < 4; n++) {
      const int Lr = 32 * (n & 1) + 8 * (m >> 2) + 4 * (n >> 1) + (m & 3);
      if (w == 0) {                      // input side 64x14, zero-pad K to 32
        s16x8 r;
        #pragma unroll
        for (int j2 = 0; j2 < 8; j2++) {
          const int kk = 8 * g + j2;
          r[j2] = (kk < F_) ? (short)f2bf(Wih0[Lr * F_ + kk]) : (short)0;
        }
        Ax[n] = r;
        Ai[n][0] = r; Ai[n][1] = r;      // dead in wave0
      } else {
        #pragma unroll
        for (int kt = 0; kt < 2; kt++)
          Ai[n][kt] = ldrow8(Wi + Lr * H_ + 32 * kt + 8 * g);
        Ax[n] = Ai[n][0];                // dead in waves 1/2
      }
      #pragma unroll
      for (int kt = 0; kt < 2; kt++)
        Ah[n][kt] = ldrow8(Wh + Lr * H_ + 32 * kt + 8 * g);
      const int Lb = 32 * (n & 1) + 8 * g + 4 * (n >> 1);
      bc[n] = *(const f32x4*)(bi + Lb) + *(const f32x4*)(bh + Lb);
    }
  }

  // ---- hh-state frags (own layer), zero init (h(-1)=0 in REGISTERS) ----
  s16x8 F[2];
  F[0] = zf; F[1] = zf;
  f32x4 h2v[4];
  #pragma unroll
  for (int n = 0; n < 4; n++) h2v[n] = z4;

  // ---- x producer helpers (wave 3 only in steady state) ----
  const float* xrow = x + (size_t)row * T_ * F_;
  auto ldraw = [&](int t, f32x4& ra, f32x4& rb) {    // R8-proven float2 loads
    const float* p = xrow + t * F_;
    if (g == 0) {
      f32x2 p0 = *(const f32x2*)(p),     p1 = *(const f32x2*)(p + 2);
      f32x2 p2 = *(const f32x2*)(p + 4), p3 = *(const f32x2*)(p + 6);
      ra[0] = p0[0]; ra[1] = p0[1]; ra[2] = p1[0]; ra[3] = p1[1];
      rb[0] = p2[0]; rb[1] = p2[1]; rb[2] = p3[0]; rb[3] = p3[1];
    } else if (g == 1) {
      f32x2 p4 = *(const f32x2*)(p + 8), p5 = *(const f32x2*)(p + 10);
      f32x2 p6 = *(const f32x2*)(p + 12);
      ra[0] = p4[0]; ra[1] = p4[1]; ra[2] = p5[0]; ra[3] = p5[1];
      rb[0] = p6[0]; rb[1] = p6[1]; rb[2] = 0.f;   rb[3] = 0.f;
    } else {
      ra = z4; rb = z4;
    }
  };
  auto cvtraw = [&](const f32x4& ra, const f32x4& rb) -> s16x8 {
    u32x4 p;
    p[0] = cvtpk(ra[0], ra[1]); p[1] = cvtpk(ra[2], ra[3]);
    p[2] = cvtpk(rb[0], rb[1]); p[3] = cvtpk(rb[2], rb[3]);
    return __builtin_bit_cast(s16x8, p);
  };

  // ---- prologue: wave3 stages chunk 0 into xbuf[0] (lanes g<2 only) ----
  if (w == 3) {
    f32x4 ra[K_], rb[K_];
    #pragma unroll
    for (int k = 0; k < K_; k++) ldraw(k, ra[k], rb[k]);
    if (g < 2) {
      #pragma unroll
      for (int k = 0; k < K_; k++)
        xbuf[0][k][lane] = __builtin_bit_cast(u32x4, cvtraw(ra[k], rb[k]));
    }
  }
  __syncthreads();

  // ---- chunked pipelined loop: epoch e, wave w does chunk c = e - w ----
  #pragma unroll 1
  for (int e = 0; e < NCH + 2; e++) {
    const int wb = e & 1, rbuf = wb ^ 1;

    if (w == 3) {
      // produce chunk e+1 into xbuf[(e+1)&1] == xbuf[rbuf]
      if (e < NCH - 1) {
        f32x4 ra[K_], rb[K_];
        #pragma unroll
        for (int k = 0; k < K_; k++) ldraw((e + 1) * K_ + k, ra[k], rb[k]);
        if (g < 2) {
          #pragma unroll
          for (int k = 0; k < K_; k++)
            xbuf[rbuf][k][lane] = __builtin_bit_cast(u32x4, cvtraw(ra[k], rb[k]));
        }
      }
    } else {
      const int c = e - w;
      if (c >= 0 && c < NCH) {           // wave-uniform
        // ---- chunk-top input fetch into registers ----
        s16x8 cur[K_];                   // wave0: x frags (chunk c, parity wb)
        f32x4 stage[2 * K_];             // waves1/2: prev-layer h frags
        if (w == 0) {
          #pragma unroll
          for (int k = 0; k < K_; k++) {
            // x-frag is zero for g>=2 (F=14); address clamped in-bounds
            s16x8 v = __builtin_bit_cast(s16x8, xbuf[wb][k][lane & 31]);
            cur[k] = (g < 2) ? v : zf;
          }
        } else {
          const int src = w - 1;
          #pragma unroll
          for (int k = 0; k < K_; k++) {
            stage[k]      = __builtin_bit_cast(f32x4, hf[rbuf][src][k][0][lane]);
            stage[K_ + k] = __builtin_bit_cast(f32x4, hf[rbuf][src][k][1][lane]);
          }
        }

        // ---- q prologue, seeded with bc (bias folded into q accumulator) ----
        f32x4 qc[4], qn[4];
        if (w == 0) {
          #pragma unroll
          for (int n = 0; n < 4; n++) qc[n] = MFMA(Ax[n], cur[0], bc[n]);
        } else {
          const s16x8 P0 = __builtin_bit_cast(s16x8, stage[0]);
          const s16x8 P1 = __builtin_bit_cast(s16x8, stage[K_]);
          #pragma unroll
          for (int n = 0; n < 4; n++) qc[n] = MFMA(Ai[n][0], P0, bc[n]);
          #pragma unroll
          for (int n = 0; n < 4; n++) qc[n] = MFMA(Ai[n][1], P1, qc[n]);
        }

        #pragma unroll
        for (int k = 0; k < K_; k++) {
          // chain first: p accumulates INTO qc (bc+q already there).
          // Tiles 0,2 first so F[0]'s inputs retire first.
          f32x4 p[4];
          p[0] = MFMA(Ah[0][0], F[0], qc[0]);
          p[2] = MFMA(Ah[2][0], F[0], qc[2]);
          p[1] = MFMA(Ah[1][0], F[0], qc[1]);
          p[3] = MFMA(Ah[3][0], F[0], qc[3]);
          p[0] = MFMA(Ah[0][1], F[1], p[0]);
          p[2] = MFMA(Ah[2][1], F[1], p[2]);
          p[1] = MFMA(Ah[1][1], F[1], p[1]);
          p[3] = MFMA(Ah[3][1], F[1], p[3]);

          // next step's q — independent, fills MFMA pipe during tanh
          if (k + 1 < K_) {
            if (w == 0) {
              #pragma unroll
              for (int n = 0; n < 4; n++) qn[n] = MFMA(Ax[n], cur[k + 1], bc[n]);
            } else {
              const s16x8 P0 = __builtin_bit_cast(s16x8, stage[k + 1]);
              const s16x8 P1 = __builtin_bit_cast(s16x8, stage[K_ + k + 1]);
              #pragma unroll
              for (int n = 0; n < 4; n++) qn[n] = MFMA(Ai[n][0], P0, bc[n]);
              #pragma unroll
              for (int n = 0; n < 4; n++) qn[n] = MFMA(Ai[n][1], P1, qn[n]);
            }
          }

          // F[0] first (tiles 0,2) so next step's first MFMA pair starts early
          f32x4 hv0 = tanh4(p[0]);
          f32x4 hv2 = tanh4(p[2]);
          F[0] = packfrag(hv0, hv2);
          f32x4 hv1 = tanh4(p[1]);
          f32x4 hv3 = tanh4(p[3]);
          F[1] = packfrag(hv1, hv3);

          if (w < 2) {
            hf[wb][w][k][0][lane] = __builtin_bit_cast(u32x4, F[0]);
            hf[wb][w][k][1][lane] = __builtin_bit_cast(u32x4, F[1]);
          } else if (c == NCH - 1 && k == K_ - 1) {
            h2v[0] = hv0; h2v[1] = hv1;    // fp32 h2 for head
            h2v[2] = hv2; h2v[3] = hv3;
          }

          if (k + 1 < K_) {
            #pragma unroll
            for (int n = 0; n < 4; n++) qc[n] = qn[n];
          }
        }
      }
    }
    __syncthreads();   // single chunk-granular barrier (R8 dbuf protocol)
  }

  // ---- FC head: h2l overlays dead hf; wave 2 un-permutes, wave 0 computes ----
  float (*h2l)[68] = (float (*)[68])smem;
  if (w == 2) {
    #pragma unroll
    for (int n = 0; n < 4; n++) {
      const int Lb = 32 * (n & 1) + 8 * g + 4 * (n >> 1);
      *(f32x4*)&h2l[m][Lb] = h2v[n];
    }
  }
  __syncthreads();

  if (w == 0) {
    float hr[64];
    #pragma unroll
    for (int q = 0; q < 16; q++) {
      f32x4 v = *(const f32x4*)&h2l[m][4 * q];
      hr[4 * q + 0] = v[0]; hr[4 * q + 1] = v[1];
      hr[4 * q + 2] = v[2]; hr[4 * q + 3] = v[3];
    }
    float acc2 = 0.f;
    #pragma unroll
    for (int jj = 0; jj < 8; jj++) {
      const int jf = 8 * g + jj;
      float s = fc1b[jf];
      const f32x4* wp = (const f32x4*)(fc1w + jf * H_);
      #pragma unroll
      for (int kq = 0; kq < 16; kq++) {
        f32x4 wv = wp[kq];
        s += hr[4 * kq + 0] * wv[0] + hr[4 * kq + 1] * wv[1]
           + hr[4 * kq + 2] * wv[2] + hr[4 * kq + 3] * wv[3];
      }
      s = fmaxf(s, 0.f);
      acc2 += s * fc2w[jf];
    }
    acc2 += __shfl_xor(acc2, 16, 64);
    acc2 += __shfl_xor(acc2, 32, 64);
    if (lane < 16) out[row] = acc2 + fc2b[0];   // clamped row; dup writes benign
  }
}

extern "C" void kernel_launch(void* const* d_in, const int* in_sizes, int n_in,
                              void* d_out, int out_size, void* d_ws, size_t ws_size,
                              hipStream_t stream) {
  const float* x    = (const float*)d_in[0];
  const float* Wih0 = (const float*)d_in[1];
  const float* Whh0 = (const float*)d_in[2];
  const float* bih0 = (const float*)d_in[3];
  const float* bhh0 = (const float*)d_in[4];
  const float* Wih1 = (const float*)d_in[5];
  const float* Whh1 = (const float*)d_in[6];
  const float* bih1 = (const float*)d_in[7];
  const float* bhh1 = (const float*)d_in[8];
  const float* Wih2 = (const float*)d_in[9];
  const float* Whh2 = (const float*)d_in[10];
  const float* bih2 = (const float*)d_in[11];
  const float* bhh2 = (const float*)d_in[12];
  const float* fc1w = (const float*)d_in[13];
  const float* fc1b = (const float*)d_in[14];
  const float* fc2w = (const float*)d_in[15];
  const float* fc2b = (const float*)d_in[16];

  static bool s_attr_set = false;
  if (!s_attr_set) {
    (void)hipFuncSetAttribute((const void*)rnn_ck,
                              hipFuncAttributeMaxDynamicSharedMemorySize,
                              SMEM_BYTES);
    s_attr_set = true;
  }

  rnn_ck<<<dim3(BTOT / BSTR), dim3(256), SMEM_BYTES, stream>>>(
      x, Wih0, Whh0, bih0, bhh0, Wih1, Whh1, bih1, bhh1,
      Wih2, Whh2, bih2, bhh2, fc1w, fc1b, fc2w, fc2b, (float*)d_out);
}

// Round 10
// 195.831 us; speedup vs baseline: 1.1997x; 1.1997x over previous
//
#include <hip/hip_runtime.h>

typedef short  s16x8 __attribute__((ext_vector_type(8)));   // 8 bf16 bit patterns
typedef float  f32x4 __attribute__((ext_vector_type(4)));
typedef float  f32x2 __attribute__((ext_vector_type(2)));
typedef unsigned int u32;
typedef unsigned int u32x4 __attribute__((ext_vector_type(4)));
typedef unsigned short u16;

#define DEVI static __device__ __forceinline__

#if __has_builtin(__builtin_amdgcn_exp2f)
#define EXP2(v) __builtin_amdgcn_exp2f(v)   // raw v_exp_f32 (R11-proven)
#else
#define EXP2(v) exp2f(v)
#endif

constexpr int T_   = 128;
constexpr int F_   = 14;
constexpr int H_   = 64;
constexpr int BPB  = 16;   // batch rows computed per block (MFMA M dim)
constexpr int BSTR = 8;    // block stride: adjacent blocks overlap 8 rows
                           // (redundant identical compute) -> 512 blocks ->
                           // 2 blocks/CU -> 2 waves/SIMD TLP
constexpr int BTOT = 4096; // total batch rows
constexpr int K_   = 8;    // timesteps per epoch (chunk)
constexpr int NCH  = T_ / K_;   // 16 chunks

// x-frag is identically ZERO for lanes g>=2 (only 14 features) -> xbuf needs
// only 32 lanes.  LDS total 72 KiB -> two blocks = 144 KiB < 160 KiB.
constexpr int HF_BYTES   = 2 * 2 * K_ * 2 * 64 * 16;   // 65536
constexpr int XBUF_BYTES = 2 * K_ * 32 * 16;           // 8192 (32 lanes only)
constexpr int SMEM_BYTES = HF_BYTES + XBUF_BYTES;      // 73728

DEVI u16 f2bf(float f) {                     // RNE, one-time weight convert
  u32 u = __builtin_bit_cast(u32, f);
  u += 0x7fffu + ((u >> 16) & 1u);
  return (u16)(u >> 16);
}
// HW packed bf16 convert (RNE): 1 instr replaces 5-op manual pack.
DEVI u32 cvtpk(float a, float b) {           // lo16 = bf16(a), hi16 = bf16(b)
  u32 r;
  asm("v_cvt_pk_bf16_f32 %0, %1, %2" : "=v"(r) : "v"(a), "v"(b));
  return r;
}
// B-frag kt from tanh'd acc tiles: elements 0-3 = tile kt, 4-7 = tile kt+2
DEVI s16x8 packfrag(const f32x4& a, const f32x4& b) {
  u32x4 p;
  p[0] = cvtpk(a[0], a[1]); p[1] = cvtpk(a[2], a[3]);
  p[2] = cvtpk(b[0], b[1]); p[3] = cvtpk(b[2], b[3]);
  return __builtin_bit_cast(s16x8, p);
}
// tanh; mul/add/fma as packed fp32 (bit-identical to scalar), trans scalar.
DEVI f32x4 tanh4(const f32x4& v) {
  const f32x4 kC = -2.8853900817779268f;
  f32x4 t = v * kC;                          // 2x v_pk_mul_f32
  f32x4 e;
  e[0] = EXP2(t[0]); e[1] = EXP2(t[1]);
  e[2] = EXP2(t[2]); e[3] = EXP2(t[3]);
  const f32x4 kOne = 1.0f;
  f32x4 d = e + kOne;                        // 2x v_pk_add_f32
  f32x4 r;
  r[0] = __builtin_amdgcn_rcpf(d[0]); r[1] = __builtin_amdgcn_rcpf(d[1]);
  r[2] = __builtin_amdgcn_rcpf(d[2]); r[3] = __builtin_amdgcn_rcpf(d[3]);
  const f32x4 kTwo = 2.0f, kNegOne = -1.0f;
  return __builtin_elementwise_fma(kTwo, r, kNegOne);   // 2x v_pk_fma_f32
}
DEVI f32x4 MFMA(s16x8 a, s16x8 b, f32x4 c) {
  return __builtin_amdgcn_mfma_f32_16x16x32_bf16(a, b, c, 0, 0, 0);
}
DEVI s16x8 ldrow8(const float* p) {          // 8 contiguous fp32 -> bf16 A-frag
  const f32x4 a = ((const f32x4*)p)[0];
  const f32x4 b = ((const f32x4*)p)[1];
  s16x8 r;
  r[0] = (short)f2bf(a[0]); r[1] = (short)f2bf(a[1]);
  r[2] = (short)f2bf(a[2]); r[3] = (short)f2bf(a[3]);
  r[4] = (short)f2bf(b[0]); r[5] = (short)f2bf(b[1]);
  r[6] = (short)f2bf(b[2]); r[7] = (short)f2bf(b[3]);
  return r;
}

// R10: duplicate-work TLP (R5-proven co-residency, R9-proven numerics) with
// the register shortfall removed.  R9 vs R5 isolated the co-residency lever:
// __launch_bounds__(256,2) (total regs <= 256/wave incl. AGPRs) is required
// for 2 blocks/CU; R5 spilled under it because ~176 arch regs were live.
// THIS ROUND cuts true register need to fit the clamp:
//  * per-step LDS reads (1-step-ahead) replace the chunk-top stage[16]/cur[8]
//    register caches (-56/-24 regs; same read count, same parity protocol)
//  * producer stages 4 timesteps at a time (half-burst, -32 regs)
//  * accumulators (qc/qn/p, bc) are MFMA C-operands -> acc file under clamp
// Arithmetic chain identical to R3/R5/R9 -> absmax exactly 5.859375e-3.
__global__ __launch_bounds__(256, 2) void rnn_ck(
    const float* __restrict__ x,
    const float* __restrict__ Wih0, const float* __restrict__ Whh0,
    const float* __restrict__ bih0, const float* __restrict__ bhh0,
    const float* __restrict__ Wih1, const float* __restrict__ Whh1,
    const float* __restrict__ bih1, const float* __restrict__ bhh1,
    const float* __restrict__ Wih2, const float* __restrict__ Whh2,
    const float* __restrict__ bih2, const float* __restrict__ bhh2,
    const float* __restrict__ fc1w, const float* __restrict__ fc1b,
    const float* __restrict__ fc2w, const float* __restrict__ fc2b,
    float* __restrict__ out)
{
  extern __shared__ __align__(16) char smem[];
  // hf[par][layer01][k][frag][lane], xbuf[par][k][lane<32]
  u32x4 (*hf)[2][K_][2][64] = (u32x4 (*)[2][K_][2][64])smem;
  u32x4 (*xbuf)[K_][32]     = (u32x4 (*)[K_][32])(smem + HF_BYTES);

  const int tid  = threadIdx.x;
  const int w    = tid >> 6;        // waves 0-2: layer id; wave 3: x producer
  const int lane = tid & 63;
  const int g    = lane >> 4;
  const int m    = lane & 15;
  const int b0   = blockIdx.x * BSTR;
  // clamped global row: last block's rows 8..15 fold to 4095 (identical
  // values recomputed; duplicate writes of identical data are benign)
  const int row  = (b0 + m < BTOT) ? (b0 + m) : (BTOT - 1);

  f32x4 z4; z4[0] = 0.f; z4[1] = 0.f; z4[2] = 0.f; z4[3] = 0.f;
  s16x8 zf;
  #pragma unroll
  for (int i = 0; i < 8; i++) zf[i] = 0;

  // ---- per-wave (per-layer) weights, register-resident (waves 0-2 only) ----
  s16x8 Ax[4], Ai[4][2], Ah[4][2];
  f32x4 bc[4];
  if (w < 3) {
    const float* Wi = Wih1; const float* Wh = Whh0;
    const float* bi = bih0; const float* bh = bhh0;
    if (w == 1)      { Wi = Wih1; Wh = Whh1; bi = bih1; bh = bhh1; }
    else if (w == 2) { Wi = Wih2; Wh = Whh2; bi = bih2; bh = bhh2; }
    #pragma unroll
    for (int n = 0; n < 4; n++) {
      const int Lr = 32 * (n & 1) + 8 * (m >> 2) + 4 * (n >> 1) + (m & 3);
      if (w == 0) {                      // input side 64x14, zero-pad K to 32
        s16x8 r;
        #pragma unroll
        for (int j2 = 0; j2 < 8; j2++) {
          const int kk = 8 * g + j2;
          r[j2] = (kk < F_) ? (short)f2bf(Wih0[Lr * F_ + kk]) : (short)0;
        }
        Ax[n] = r;
        Ai[n][0] = r; Ai[n][1] = r;      // dead in wave0
      } else {
        #pragma unroll
        for (int kt = 0; kt < 2; kt++)
          Ai[n][kt] = ldrow8(Wi + Lr * H_ + 32 * kt + 8 * g);
        Ax[n] = Ai[n][0];                // dead in waves 1/2
      }
      #pragma unroll
      for (int kt = 0; kt < 2; kt++)
        Ah[n][kt] = ldrow8(Wh + Lr * H_ + 32 * kt + 8 * g);
      const int Lb = 32 * (n & 1) + 8 * g + 4 * (n >> 1);
      bc[n] = *(const f32x4*)(bi + Lb) + *(const f32x4*)(bh + Lb);
    }
  }

  // ---- hh-state frags (own layer), zero init (h(-1)=0 in REGISTERS) ----
  s16x8 F[2];
  F[0] = zf; F[1] = zf;
  f32x4 h2v[4];
  #pragma unroll
  for (int n = 0; n < 4; n++) h2v[n] = z4;

  // ---- x producer helpers (wave 3 only in steady state) ----
  const float* xrow = x + (size_t)row * T_ * F_;
  auto ldraw = [&](int t, f32x4& ra, f32x4& rb) {    // R8-proven float2 loads
    const float* p = xrow + t * F_;
    if (g == 0) {
      f32x2 p0 = *(const f32x2*)(p),     p1 = *(const f32x2*)(p + 2);
      f32x2 p2 = *(const f32x2*)(p + 4), p3 = *(const f32x2*)(p + 6);
      ra[0] = p0[0]; ra[1] = p0[1]; ra[2] = p1[0]; ra[3] = p1[1];
      rb[0] = p2[0]; rb[1] = p2[1]; rb[2] = p3[0]; rb[3] = p3[1];
    } else if (g == 1) {
      f32x2 p4 = *(const f32x2*)(p + 8), p5 = *(const f32x2*)(p + 10);
      f32x2 p6 = *(const f32x2*)(p + 12);
      ra[0] = p4[0]; ra[1] = p4[1]; ra[2] = p5[0]; ra[3] = p5[1];
      rb[0] = p6[0]; rb[1] = p6[1]; rb[2] = 0.f;   rb[3] = 0.f;
    } else {
      ra = z4; rb = z4;
    }
  };
  auto cvtraw = [&](const f32x4& ra, const f32x4& rb) -> s16x8 {
    u32x4 p;
    p[0] = cvtpk(ra[0], ra[1]); p[1] = cvtpk(ra[2], ra[3]);
    p[2] = cvtpk(rb[0], rb[1]); p[3] = cvtpk(rb[2], rb[3]);
    return __builtin_bit_cast(s16x8, p);
  };
  // stage 4 consecutive timesteps (t0..t0+3) into xbuf[par] — 32 regs live
  auto produce4 = [&](int par, int kbase, int t0) {
    f32x4 ra[4], rb[4];
    #pragma unroll
    for (int t = 0; t < 4; t++) ldraw(t0 + t, ra[t], rb[t]);
    if (g < 2) {
      #pragma unroll
      for (int t = 0; t < 4; t++)
        xbuf[par][kbase + t][lane] =
            __builtin_bit_cast(u32x4, cvtraw(ra[t], rb[t]));
    }
  };

  // ---- prologue: wave3 stages chunk 0 into xbuf[0] (two half-bursts) ----
  if (w == 3) {
    produce4(0, 0, 0);
    produce4(0, 4, 4);
  }
  __syncthreads();

  // ---- chunked pipelined loop: epoch e, wave w does chunk c = e - w ----
  #pragma unroll 1
  for (int e = 0; e < NCH + 2; e++) {
    const int wb = e & 1, rbuf = wb ^ 1;

    if (w == 3) {
      // produce chunk e+1 into xbuf[rbuf] (two half-bursts, 32 regs live)
      if (e < NCH - 1) {
        const int t0 = (e + 1) * K_;
        produce4(rbuf, 0, t0);
        produce4(rbuf, 4, t0 + 4);
      }
    } else {
      const int c = e - w;
      if (c >= 0 && c < NCH) {           // wave-uniform
        const int src = w - 1;           // (unused for w==0)

        // ---- step-0 inputs (fresh LDS reads at chunk top) ----
        s16x8 xc; f32x4 P0c, P1c;
        if (w == 0) {
          s16x8 v = __builtin_bit_cast(s16x8, xbuf[wb][0][lane & 31]);
          xc = (g < 2) ? v : zf;
        } else {
          P0c = __builtin_bit_cast(f32x4, hf[rbuf][src][0][0][lane]);
          P1c = __builtin_bit_cast(f32x4, hf[rbuf][src][0][1][lane]);
        }

        // ---- q prologue, seeded with bc (bias folded into q accumulator) ----
        f32x4 qc[4], qn[4];
        if (w == 0) {
          #pragma unroll
          for (int n = 0; n < 4; n++) qc[n] = MFMA(Ax[n], xc, bc[n]);
        } else {
          const s16x8 P0 = __builtin_bit_cast(s16x8, P0c);
          const s16x8 P1 = __builtin_bit_cast(s16x8, P1c);
          #pragma unroll
          for (int n = 0; n < 4; n++) qc[n] = MFMA(Ai[n][0], P0, bc[n]);
          #pragma unroll
          for (int n = 0; n < 4; n++) qc[n] = MFMA(Ai[n][1], P1, qc[n]);
        }

        #pragma unroll
        for (int k = 0; k < K_; k++) {
          // issue next step's input reads NOW (consumed after the p-chain)
          s16x8 xn; f32x4 P0n, P1n;
          if (k + 1 < K_) {
            if (w == 0) {
              s16x8 v = __builtin_bit_cast(s16x8, xbuf[wb][k + 1][lane & 31]);
              xn = (g < 2) ? v : zf;
            } else {
              P0n = __builtin_bit_cast(f32x4, hf[rbuf][src][k + 1][0][lane]);
              P1n = __builtin_bit_cast(f32x4, hf[rbuf][src][k + 1][1][lane]);
            }
          }

          // chain first: p accumulates INTO qc (bc+q already there).
          // Tiles 0,2 first so F[0]'s inputs retire first.
          f32x4 p[4];
          p[0] = MFMA(Ah[0][0], F[0], qc[0]);
          p[2] = MFMA(Ah[2][0], F[0], qc[2]);
          p[1] = MFMA(Ah[1][0], F[0], qc[1]);
          p[3] = MFMA(Ah[3][0], F[0], qc[3]);
          p[0] = MFMA(Ah[0][1], F[1], p[0]);
          p[2] = MFMA(Ah[2][1], F[1], p[2]);
          p[1] = MFMA(Ah[1][1], F[1], p[1]);
          p[3] = MFMA(Ah[3][1], F[1], p[3]);

          // next step's q — independent, fills MFMA pipe during tanh
          if (k + 1 < K_) {
            if (w == 0) {
              #pragma unroll
              for (int n = 0; n < 4; n++) qn[n] = MFMA(Ax[n], xn, bc[n]);
            } else {
              const s16x8 P0 = __builtin_bit_cast(s16x8, P0n);
              const s16x8 P1 = __builtin_bit_cast(s16x8, P1n);
              #pragma unroll
              for (int n = 0; n < 4; n++) qn[n] = MFMA(Ai[n][0], P0, bc[n]);
              #pragma unroll
              for (int n = 0; n < 4; n++) qn[n] = MFMA(Ai[n][1], P1, qn[n]);
            }
          }

          // F[0] first (tiles 0,2) so next step's first MFMA pair starts early
          f32x4 hv0 = tanh4(p[0]);
          f32x4 hv2 = tanh4(p[2]);
          F[0] = packfrag(hv0, hv2);
          f32x4 hv1 = tanh4(p[1]);
          f32x4 hv3 = tanh4(p[3]);
          F[1] = packfrag(hv1, hv3);

          if (w < 2) {
            hf[wb][w][k][0][lane] = __builtin_bit_cast(u32x4, F[0]);
            hf[wb][w][k][1][lane] = __builtin_bit_cast(u32x4, F[1]);
          } else if (c == NCH - 1 && k == K_ - 1) {
            h2v[0] = hv0; h2v[1] = hv1;    // fp32 h2 for head
            h2v[2] = hv2; h2v[3] = hv3;
          }

          if (k + 1 < K_) {
            #pragma unroll
            for (int n = 0; n < 4; n++) qc[n] = qn[n];
          }
        }
      }
    }
    __syncthreads();   // single chunk-granular barrier (R8 dbuf protocol)
  }

  // ---- FC head: h2l overlays dead hf; wave 2 un-permutes, wave 0 computes ----
  float (*h2l)[68] = (float (*)[68])smem;
  if (w == 2) {
    #pragma unroll
    for (int n = 0; n < 4; n++) {
      const int Lb = 32 * (n & 1) + 8 * g + 4 * (n >> 1);
      *(f32x4*)&h2l[m][Lb] = h2v[n];
    }
  }
  __syncthreads();

  if (w == 0) {
    float hr[64];
    #pragma unroll
    for (int q = 0; q < 16; q++) {
      f32x4 v = *(const f32x4*)&h2l[m][4 * q];
      hr[4 * q + 0] = v[0]; hr[4 * q + 1] = v[1];
      hr[4 * q + 2] = v[2]; hr[4 * q + 3] = v[3];
    }
    float acc2 = 0.f;
    #pragma unroll
    for (int jj = 0; jj < 8; jj++) {
      const int jf = 8 * g + jj;
      float s = fc1b[jf];
      const f32x4* wp = (const f32x4*)(fc1w + jf * H_);
      #pragma unroll
      for (int kq = 0; kq < 16; kq++) {
        f32x4 wv = wp[kq];
        s += hr[4 * kq + 0] * wv[0] + hr[4 * kq + 1] * wv[1]
           + hr[4 * kq + 2] * wv[2] + hr[4 * kq + 3] * wv[3];
      }
      s = fmaxf(s, 0.f);
      acc2 += s * fc2w[jf];
    }
    acc2 += __shfl_xor(acc2, 16, 64);
    acc2 += __shfl_xor(acc2, 32, 64);
    if (lane < 16) out[row] = acc2 + fc2b[0];   // clamped row; dup writes benign
  }
}

extern "C" void kernel_launch(void* const* d_in, const int* in_sizes, int n_in,
                              void* d_out, int out_size, void* d_ws, size_t ws_size,
                              hipStream_t stream) {
  const float* x    = (const float*)d_in[0];
  const float* Wih0 = (const float*)d_in[1];
  const float* Whh0 = (const float*)d_in[2];
  const float* bih0 = (const float*)d_in[3];
  const float* bhh0 = (const float*)d_in[4];
  const float* Wih1 = (const float*)d_in[5];
  const float* Whh1 = (const float*)d_in[6];
  const float* bih1 = (const float*)d_in[7];
  const float* bhh1 = (const float*)d_in[8];
  const float* Wih2 = (const float*)d_in[9];
  const float* Whh2 = (const float*)d_in[10];
  const float* bih2 = (const float*)d_in[11];
  const float* bhh2 = (const float*)d_in[12];
  const float* fc1w = (const float*)d_in[13];
  const float* fc1b = (const float*)d_in[14];
  const float* fc2w = (const float*)d_in[15];
  const float* fc2b = (const float*)d_in[16];

  static bool s_attr_set = false;
  if (!s_attr_set) {
    (void)hipFuncSetAttribute((const void*)rnn_ck,
                              hipFuncAttributeMaxDynamicSharedMemorySize,
                              SMEM_BYTES);
    s_attr_set = true;
  }

  rnn_ck<<<dim3(BTOT / BSTR), dim3(256), SMEM_BYTES, stream>>>(
      x, Wih0, Whh0, bih0, bhh0, Wih1, Whh1, bih1, bhh1,
      Wih2, Whh2, bih2, bhh2, fc1w, fc1b, fc2w, fc2b, (float*)d_out);
}

// Round 12
// 160.730 us; speedup vs baseline: 1.4616x; 1.2184x over previous
//
#include <hip/hip_runtime.h>

typedef short  s16x8 __attribute__((ext_vector_type(8)));   // 8 bf16 bit patterns
typedef float  f32x4 __attribute__((ext_vector_type(4)));
typedef float  f32x2 __attribute__((ext_vector_type(2)));
typedef unsigned int u32;
typedef unsigned int u32x4 __attribute__((ext_vector_type(4)));
typedef unsigned short u16;

#define DEVI static __device__ __forceinline__

#if __has_builtin(__builtin_amdgcn_exp2f)
#define EXP2(v) __builtin_amdgcn_exp2f(v)   // raw v_exp_f32 (R11-proven)
#else
#define EXP2(v) exp2f(v)
#endif

constexpr int T_  = 128;
constexpr int F_  = 14;
constexpr int H_  = 64;
constexpr int BPB = 16;        // batch rows per block (grid 256, non-redundant)
constexpr int K_  = 4;         // timesteps per epoch (chunk)
constexpr int NCH = T_ / K_;   // 32 chunks

// LDS: hf (h frags, layers 0/1) + xbuf (x frags) + qbuf (fp32 q = bc + Wih*in)
constexpr int HF_BYTES   = 2 * 2 * K_ * 2 * 64 * 16;     // 32768
constexpr int XBUF_BYTES = 2 * K_ * 64 * 16;             // 8192
constexpr int QBUF_BYTES = 2 * 3 * K_ * 4 * 64 * 16;     // 98304
constexpr int SMEM_BYTES = HF_BYTES + XBUF_BYTES + QBUF_BYTES;  // 139264

DEVI u16 f2bf(float f) {                     // RNE, one-time weight convert
  u32 u = __builtin_bit_cast(u32, f);
  u += 0x7fffu + ((u >> 16) & 1u);
  return (u16)(u >> 16);
}
DEVI u32 cvtpk(float a, float b) {           // HW packed bf16 cvt (RNE)
  u32 r;
  asm("v_cvt_pk_bf16_f32 %0, %1, %2" : "=v"(r) : "v"(a), "v"(b));
  return r;
}
// B-frag kt from tanh'd acc tiles: elements 0-3 = tile kt, 4-7 = tile kt+2
DEVI s16x8 packfrag(const f32x4& a, const f32x4& b) {
  u32x4 p;
  p[0] = cvtpk(a[0], a[1]); p[1] = cvtpk(a[2], a[3]);
  p[2] = cvtpk(b[0], b[1]); p[3] = cvtpk(b[2], b[3]);
  return __builtin_bit_cast(s16x8, p);
}
// tanh; mul/add/fma as packed fp32 (bit-identical to scalar), trans scalar.
DEVI f32x4 tanh4(const f32x4& v) {
  const f32x4 kC = -2.8853900817779268f;
  f32x4 t = v * kC;
  f32x4 e;
  e[0] = EXP2(t[0]); e[1] = EXP2(t[1]);
  e[2] = EXP2(t[2]); e[3] = EXP2(t[3]);
  const f32x4 kOne = 1.0f;
  f32x4 d = e + kOne;
  f32x4 r;
  r[0] = __builtin_amdgcn_rcpf(d[0]); r[1] = __builtin_amdgcn_rcpf(d[1]);
  r[2] = __builtin_amdgcn_rcpf(d[2]); r[3] = __builtin_amdgcn_rcpf(d[3]);
  const f32x4 kTwo = 2.0f, kNegOne = -1.0f;
  return __builtin_elementwise_fma(kTwo, r, kNegOne);
}
DEVI f32x4 MFMA(s16x8 a, s16x8 b, f32x4 c) {
  return __builtin_amdgcn_mfma_f32_16x16x32_bf16(a, b, c, 0, 0, 0);
}
DEVI s16x8 ldrow8(const float* p) {          // 8 contiguous fp32 -> bf16 A-frag
  const f32x4 a = ((const f32x4*)p)[0];
  const f32x4 b = ((const f32x4*)p)[1];
  s16x8 r;
  r[0] = (short)f2bf(a[0]); r[1] = (short)f2bf(a[1]);
  r[2] = (short)f2bf(a[2]); r[3] = (short)f2bf(a[3]);
  r[4] = (short)f2bf(b[0]); r[5] = (short)f2bf(b[1]);
  r[6] = (short)f2bf(b[2]); r[7] = (short)f2bf(b[3]);
  return r;
}

// R12 = R11 VERBATIM resubmit.  R11 died with "container failed twice" and
// zero test output — the same infra signature as R6, whose identical
// resubmission (R7) ran fine.  Two independent audits of R11 found no hang
// source (uniform barriers incl. idle wv7; stage-chain parity separation
// re-derived; no OOB; LDS 136K < 160K).  Resubmitting unchanged to keep the
// infra-vs-kernel discrimination clean.
//
// Design: q/p wave split for NON-REDUNDANT 2 waves/SIMD.  8 waves, 256
// blocks, K_=4:
//   wv0..2 = B(l): recurrence-only wave for layer l.  Per step: read fp32
//            q[k] from qbuf, p = MFMA(Ah0,F0,q); MFMA(Ah1,F1,p); tanh; pack.
//            Chain is R3-VERBATIM (q is the same C-seed value, LDS hop is
//            bit-exact) -> absmax must be exactly 5.859375e-3.
//   wv4..6 = A(l): q producer.  q[k] = bc + Ai0*P0[k] + Ai1*P1[k] (R3 order),
//            P from hf (layer l-1) or xbuf (layer 0).  Runs 1 epoch ahead.
//   wv3    = x producer (chunk e at epoch e, chunk 0 in prologue).
//   wv7    = idle (barriers only).
// Stage chain prod->A0->B0->A1->B1->A2->B2, each 1 epoch apart; every buffer
// parity-double-buffered with the R3 wb/rbuf protocol; ONE __syncthreads per
// epoch (38 epochs).  SIMD pairing wv&3: each B shares its SIMD with a light
// A wave -> stalls filled, zero redundant work.
__global__ __launch_bounds__(512, 1) void rnn_ck(
    const float* __restrict__ x,
    const float* __restrict__ Wih0, const float* __restrict__ Whh0,
    const float* __restrict__ bih0, const float* __restrict__ bhh0,
    const float* __restrict__ Wih1, const float* __restrict__ Whh1,
    const float* __restrict__ bih1, const float* __restrict__ bhh1,
    const float* __restrict__ Wih2, const float* __restrict__ Whh2,
    const float* __restrict__ bih2, const float* __restrict__ bhh2,
    const float* __restrict__ fc1w, const float* __restrict__ fc1b,
    const float* __restrict__ fc2w, const float* __restrict__ fc2b,
    float* __restrict__ out)
{
  extern __shared__ __align__(16) char smem[];
  // hf[par][layer01][k][frag][lane]; xbuf[par][k][lane]; qbuf[par][layer][k][tile][lane]
  u32x4 (*hf)[2][K_][2][64]   = (u32x4 (*)[2][K_][2][64])smem;
  u32x4 (*xbuf)[K_][64]       = (u32x4 (*)[K_][64])(smem + HF_BYTES);
  f32x4 (*qbuf)[3][K_][4][64] = (f32x4 (*)[3][K_][4][64])(smem + HF_BYTES + XBUF_BYTES);

  const int tid  = threadIdx.x;
  const int wv   = tid >> 6;
  const int lane = tid & 63;
  const int g    = lane >> 4;
  const int m    = lane & 15;
  const int b0   = blockIdx.x * BPB;

  const bool isB = (wv < 3);
  const bool isP = (wv == 3);
  const bool isA = (wv >= 4 && wv < 7);
  const int  l   = isB ? wv : (wv - 4);   // layer for A/B roles (unused else)

  f32x4 z4; z4[0] = 0.f; z4[1] = 0.f; z4[2] = 0.f; z4[3] = 0.f;
  s16x8 zf;
  #pragma unroll
  for (int i = 0; i < 8; i++) zf[i] = 0;

  // ---- role weights (R3 Lr/Lb algebra, split by role) ----
  s16x8 Ax[4], Ai[4][2], Ah[4][2];
  f32x4 bc[4];
  if (isB) {
    const float* Wh = (l == 0) ? Whh0 : (l == 1) ? Whh1 : Whh2;
    #pragma unroll
    for (int n = 0; n < 4; n++) {
      const int Lr = 32 * (n & 1) + 8 * (m >> 2) + 4 * (n >> 1) + (m & 3);
      Ah[n][0] = ldrow8(Wh + Lr * H_ + 8 * g);
      Ah[n][1] = ldrow8(Wh + Lr * H_ + 32 + 8 * g);
    }
  } else if (isA) {
    const float* Wi = (l == 1) ? Wih1 : Wih2;          // l==0 uses Wih0 below
    const float* bi = (l == 0) ? bih0 : (l == 1) ? bih1 : bih2;
    const float* bh = (l == 0) ? bhh0 : (l == 1) ? bhh1 : bhh2;
    #pragma unroll
    for (int n = 0; n < 4; n++) {
      const int Lr = 32 * (n & 1) + 8 * (m >> 2) + 4 * (n >> 1) + (m & 3);
      if (l == 0) {                       // input side 64x14, zero-pad K to 32
        s16x8 r;
        #pragma unroll
        for (int j2 = 0; j2 < 8; j2++) {
          const int kk = 8 * g + j2;
          r[j2] = (kk < F_) ? (short)f2bf(Wih0[Lr * F_ + kk]) : (short)0;
        }
        Ax[n] = r;
      } else {
        Ai[n][0] = ldrow8(Wi + Lr * H_ + 8 * g);
        Ai[n][1] = ldrow8(Wi + Lr * H_ + 32 + 8 * g);
      }
      const int Lb = 32 * (n & 1) + 8 * g + 4 * (n >> 1);
      bc[n] = *(const f32x4*)(bi + Lb) + *(const f32x4*)(bh + Lb);
    }
  }

  // ---- B state: own-layer h frags, h(-1)=0 in registers ----
  s16x8 F[2];
  F[0] = zf; F[1] = zf;
  f32x4 h2v[4];
  #pragma unroll
  for (int n = 0; n < 4; n++) h2v[n] = z4;

  // ---- x producer helpers (wv3) ----
  const float* xrow = x + (size_t)(b0 + m) * T_ * F_;
  auto ldraw = [&](int t, f32x4& ra, f32x4& rb) {    // R8-proven float2 loads
    const float* p = xrow + t * F_;
    if (g == 0) {
      f32x2 p0 = *(const f32x2*)(p),     p1 = *(const f32x2*)(p + 2);
      f32x2 p2 = *(const f32x2*)(p + 4), p3 = *(const f32x2*)(p + 6);
      ra[0] = p0[0]; ra[1] = p0[1]; ra[2] = p1[0]; ra[3] = p1[1];
      rb[0] = p2[0]; rb[1] = p2[1]; rb[2] = p3[0]; rb[3] = p3[1];
    } else if (g == 1) {
      f32x2 p4 = *(const f32x2*)(p + 8), p5 = *(const f32x2*)(p + 10);
      f32x2 p6 = *(const f32x2*)(p + 12);
      ra[0] = p4[0]; ra[1] = p4[1]; ra[2] = p5[0]; ra[3] = p5[1];
      rb[0] = p6[0]; rb[1] = p6[1]; rb[2] = 0.f;   rb[3] = 0.f;
    } else {
      ra = z4; rb = z4;
    }
  };
  auto cvtraw = [&](const f32x4& ra, const f32x4& rb) -> s16x8 {
    u32x4 p;
    p[0] = cvtpk(ra[0], ra[1]); p[1] = cvtpk(ra[2], ra[3]);
    p[2] = cvtpk(rb[0], rb[1]); p[3] = cvtpk(rb[2], rb[3]);
    return __builtin_bit_cast(s16x8, p);
  };
  auto stage4 = [&](int par, int t0) {     // one chunk (4 timesteps) -> xbuf
    f32x4 ra[K_], rb[K_];
    #pragma unroll
    for (int k = 0; k < K_; k++) ldraw(t0 + k, ra[k], rb[k]);
    #pragma unroll
    for (int k = 0; k < K_; k++)
      xbuf[par][k][lane] = __builtin_bit_cast(u32x4, cvtraw(ra[k], rb[k]));
  };

  // ---- prologue: producer stages chunk 0 into xbuf[0] ----
  if (isP) stage4(0, 0);
  __syncthreads();

  // ---- main loop: 1 barrier/epoch; stage chain 1 epoch apart per hop ----
  // prod: chunk e (e in [1,NCH))       -> xbuf[wb]
  // A(l): chunk e-(2l+1)               reads prev stage [rbuf], writes qbuf[wb]
  // B(l): chunk e-(2l+2)               reads qbuf[rbuf],  writes hf[wb] (l<2)
  #pragma unroll 1
  for (int e = 0; e < NCH + 6; e++) {
    const int wb = e & 1, rbuf = wb ^ 1;

    if (isP) {
      if (e >= 1 && e < NCH) stage4(wb, e * K_);
    } else if (isA) {
      const int c = e - (2 * l + 1);
      if (c >= 0 && c < NCH) {
        if (l == 0) {
          #pragma unroll
          for (int k = 0; k < K_; k++) {
            const s16x8 xf = __builtin_bit_cast(s16x8, xbuf[rbuf][k][lane]);
            #pragma unroll
            for (int n = 0; n < 4; n++)
              qbuf[wb][0][k][n][lane] = MFMA(Ax[n], xf, bc[n]);
          }
        } else {
          #pragma unroll
          for (int k = 0; k < K_; k++) {
            const s16x8 P0 = __builtin_bit_cast(s16x8, hf[rbuf][l - 1][k][0][lane]);
            const s16x8 P1 = __builtin_bit_cast(s16x8, hf[rbuf][l - 1][k][1][lane]);
            f32x4 q[4];
            #pragma unroll
            for (int n = 0; n < 4; n++) q[n] = MFMA(Ai[n][0], P0, bc[n]);
            #pragma unroll
            for (int n = 0; n < 4; n++) q[n] = MFMA(Ai[n][1], P1, q[n]);
            #pragma unroll
            for (int n = 0; n < 4; n++) qbuf[wb][l][k][n][lane] = q[n];
          }
        }
      }
    } else if (isB) {
      const int c = e - (2 * l + 2);
      if (c >= 0 && c < NCH) {
        #pragma unroll
        for (int k = 0; k < K_; k++) {
          // fp32 q from qbuf (bit-exact R3 C-seed)
          const f32x4 qc0 = qbuf[rbuf][l][k][0][lane];
          const f32x4 qc1 = qbuf[rbuf][l][k][1][lane];
          const f32x4 qc2 = qbuf[rbuf][l][k][2][lane];
          const f32x4 qc3 = qbuf[rbuf][l][k][3][lane];
          // R3-verbatim p-chain: tiles 0,2 first so F[0] retires first
          f32x4 p[4];
          p[0] = MFMA(Ah[0][0], F[0], qc0);
          p[2] = MFMA(Ah[2][0], F[0], qc2);
          p[1] = MFMA(Ah[1][0], F[0], qc1);
          p[3] = MFMA(Ah[3][0], F[0], qc3);
          p[0] = MFMA(Ah[0][1], F[1], p[0]);
          p[2] = MFMA(Ah[2][1], F[1], p[2]);
          p[1] = MFMA(Ah[1][1], F[1], p[1]);
          p[3] = MFMA(Ah[3][1], F[1], p[3]);

          f32x4 hv0 = tanh4(p[0]);
          f32x4 hv2 = tanh4(p[2]);
          F[0] = packfrag(hv0, hv2);
          f32x4 hv1 = tanh4(p[1]);
          f32x4 hv3 = tanh4(p[3]);
          F[1] = packfrag(hv1, hv3);

          if (l < 2) {
            hf[wb][l][k][0][lane] = __builtin_bit_cast(u32x4, F[0]);
            hf[wb][l][k][1][lane] = __builtin_bit_cast(u32x4, F[1]);
          } else if (c == NCH - 1 && k == K_ - 1) {
            h2v[0] = hv0; h2v[1] = hv1;    // fp32 h2 for head
            h2v[2] = hv2; h2v[3] = hv3;
          }
        }
      }
    }
    __syncthreads();   // single epoch-granular barrier (R3 dbuf protocol)
  }

  // ---- FC head: h2l overlays dead smem; B2 (wv2) un-permutes, B0 computes --
  float (*h2l)[68] = (float (*)[68])smem;
  if (wv == 2) {
    #pragma unroll
    for (int n = 0; n < 4; n++) {
      const int Lb = 32 * (n & 1) + 8 * g + 4 * (n >> 1);
      *(f32x4*)&h2l[m][Lb] = h2v[n];
    }
  }
  __syncthreads();

  if (wv == 0) {
    float hr[64];
    #pragma unroll
    for (int q = 0; q < 16; q++) {
      f32x4 v = *(const f32x4*)&h2l[m][4 * q];
      hr[4 * q + 0] = v[0]; hr[4 * q + 1] = v[1];
      hr[4 * q + 2] = v[2]; hr[4 * q + 3] = v[3];
    }
    float acc2 = 0.f;
    #pragma unroll
    for (int jj = 0; jj < 8; jj++) {
      const int jf = 8 * g + jj;
      float s = fc1b[jf];
      const f32x4* wp = (const f32x4*)(fc1w + jf * H_);
      #pragma unroll
      for (int kq = 0; kq < 16; kq++) {
        f32x4 wv2 = wp[kq];
        s += hr[4 * kq + 0] * wv2[0] + hr[4 * kq + 1] * wv2[1]
           + hr[4 * kq + 2] * wv2[2] + hr[4 * kq + 3] * wv2[3];
      }
      s = fmaxf(s, 0.f);
      acc2 += s * fc2w[jf];
    }
    acc2 += __shfl_xor(acc2, 16, 64);
    acc2 += __shfl_xor(acc2, 32, 64);
    if (lane < 16) out[b0 + m] = acc2 + fc2b[0];
  }
}

extern "C" void kernel_launch(void* const* d_in, const int* in_sizes, int n_in,
                              void* d_out, int out_size, void* d_ws, size_t ws_size,
                              hipStream_t stream) {
  const float* x    = (const float*)d_in[0];
  const float* Wih0 = (const float*)d_in[1];
  const float* Whh0 = (const float*)d_in[2];
  const float* bih0 = (const float*)d_in[3];
  const float* bhh0 = (const float*)d_in[4];
  const float* Wih1 = (const float*)d_in[5];
  const float* Whh1 = (const float*)d_in[6];
  const float* bih1 = (const float*)d_in[7];
  const float* bhh1 = (const float*)d_in[8];
  const float* Wih2 = (const float*)d_in[9];
  const float* Whh2 = (const float*)d_in[10];
  const float* bih2 = (const float*)d_in[11];
  const float* bhh2 = (const float*)d_in[12];
  const float* fc1w = (const float*)d_in[13];
  const float* fc1b = (const float*)d_in[14];
  const float* fc2w = (const float*)d_in[15];
  const float* fc2b = (const float*)d_in[16];

  static bool s_attr_set = false;
  if (!s_attr_set) {
    (void)hipFuncSetAttribute((const void*)rnn_ck,
                              hipFuncAttributeMaxDynamicSharedMemorySize,
                              SMEM_BYTES);
    s_attr_set = true;
  }

  rnn_ck<<<dim3(4096 / BPB), dim3(512), SMEM_BYTES, stream>>>(
      x, Wih0, Whh0, bih0, bhh0, Wih1, Whh1, bih1, bhh1,
      Wih2, Whh2, bih2, bhh2, fc1w, fc1b, fc2w, fc2b, (float*)d_out);
}